// Round 4
// baseline (1784.359 us; speedup 1.0000x reference)
//
#include <hip/hip_runtime.h>
#include <hip/hip_cooperative_groups.h>

namespace cg = cooperative_groups;

#define HH 512
#define WW 512
#define NC 25              // final channel count: 1 + 12*2
#define HWs (HH * WW)

struct Params {
    const float* x;
    const float* bias;
    const float* w[12];
    float* out;
};

__device__ __forceinline__ int refl(int p, int n) {
    p = (p < 0) ? -p : p;
    p = (p >= n) ? (2 * n - 2 - p) : p;
    return p;
}

// Dilation-symmetry register reuse, 4-row variant: thread owns FOUR output
// rows spaced DIL apart (one column). The 6 loaded rows {h-d..h+4d} x 3
// col-taps serve all 36 row-taps: 18 dword loads per 4 px. Lane = consecutive
// col -> dense 256B wave-loads; row bases scalar. For every DIL in 1..12,
// DM + TCH == 128, so each layer is EXACTLY 1024 blocks of 256 threads ->
// perfect persistent-grid mapping (1 unit per block per layer, no work loop).
template <int NIN, int DIL>
__device__ __forceinline__ void layer_body(const float* __restrict__ wts,
                                           const float* __restrict__ bias,
                                           float* __restrict__ buf,
                                           const int layer, const int t) {
    constexpr int M4 = 512 / (4 * DIL);
    constexpr int DM = DIL * M4;          // row-bases per image
    constexpr int SPAN = 4 * DM;          // rows covered by main path
    constexpr int RT = 512 - SPAN;        // tail rows (0..32)
    constexpr int TCH = (RT + 3) / 4;     // tail chunks of 4 rows
    constexpr int IMT = 512 * DM;         // main threads per image
    constexpr int NMAIN = 4 * IMT;

    const float b0 = bias[2 * layer];
    const float b1 = bias[2 * layer + 1];

    if (t < NMAIN) {
        const int img = t / IMT;                       // uniform per block
        const int u = t - img * IMT;
        const int bi = __builtin_amdgcn_readfirstlane(u >> 9);   // base index
        const int w = u & 511;                         // per-lane column
        const int k = bi / DIL, j = bi - k * DIL;
        const int h = 4 * DIL * k + j;                 // base output row (scalar)

        int rowoff[6];                                 // rows h+(r-1)*d, scalar
#pragma unroll
        for (int r = 0; r < 6; ++r) rowoff[r] = refl(h + (r - 1) * DIL, HH) * WW;
        int cw[3];                                     // per-lane col taps
#pragma unroll
        for (int q = 0; q < 3; ++q) cw[q] = refl(w + (q - 1) * DIL, WW);

        float a0[4] = {b0, b0, b0, b0};
        float a1[4] = {b1, b1, b1, b1};
        const float* base = buf + (size_t)img * NC * HWs;

        // preload channel 0 pixel block
        float v[6][3];
#pragma unroll
        for (int r = 0; r < 6; ++r) {
            const float* rowp = base + rowoff[r];
#pragma unroll
            for (int q = 0; q < 3; ++q) v[r][q] = rowp[cw[q]];
        }

#pragma unroll
        for (int c = 0; c < NIN; ++c) {
            // ---- prefetch channel c+1 pixels while FMAs of channel c run ----
            float vn[6][3];
            if (c + 1 < NIN) {
                const float* pn = base + (size_t)(c + 1) * HWs;
#pragma unroll
                for (int r = 0; r < 6; ++r) {
                    const float* rowp = pn + rowoff[r];
#pragma unroll
                    for (int q = 0; q < 3; ++q) vn[r][q] = rowp[cw[q]];
                }
            }

            float wk0[9], wk1[9];
#pragma unroll
            for (int kk = 0; kk < 9; ++kk) {
                wk0[kk] = wts[c * 9 + kk];             // uniform -> s_load
                wk1[kk] = wts[(NIN + c) * 9 + kk];
            }

            // ---- 72 FMAs on the resident channel ----
#pragma unroll
            for (int al = 0; al < 4; ++al)
#pragma unroll
                for (int kr = 0; kr < 3; ++kr)
#pragma unroll
                    for (int kw = 0; kw < 3; ++kw) {
                        float vv = v[al + kr][kw];
                        a0[al] = fmaf(vv, wk0[kr * 3 + kw], a0[al]);
                        a1[al] = fmaf(vv, wk1[kr * 3 + kw], a1[al]);
                    }

            // ---- rotate (SSA-renamed away under full unroll) ----
            if (c + 1 < NIN) {
#pragma unroll
                for (int r = 0; r < 6; ++r)
#pragma unroll
                    for (int q = 0; q < 3; ++q) v[r][q] = vn[r][q];
            }
        }

        float* o0 = buf + (size_t)(img * NC + NIN) * HWs;
        float* o1 = o0 + HWs;
#pragma unroll
        for (int al = 0; al < 4; ++al) {
            size_t off = (size_t)(h + al * DIL) * WW + (size_t)w;
            o0[off] = fmaxf(a0[al], 0.f);
            o1[off] = fmaxf(a1[al], 0.f);
        }
    } else if (RT > 0) {
        const int t2 = t - NMAIN;
        constexpr int PIT = 512 * TCH;
        const int img = t2 / PIT;
        const int u = t2 - img * PIT;
        const int s = __builtin_amdgcn_readfirstlane(u >> 9);
        const int w = u & 511;
        const int r0 = SPAN + 4 * s;

        int cw[3];
#pragma unroll
        for (int q = 0; q < 3; ++q) cw[q] = refl(w + (q - 1) * DIL, WW);
        int ro[3][4];
#pragma unroll
        for (int kr = 0; kr < 3; ++kr)
#pragma unroll
            for (int i = 0; i < 4; ++i)
                ro[kr][i] = refl(r0 + i + (kr - 1) * DIL, HH) * WW;

        float a0[4] = {b0, b0, b0, b0};
        float a1[4] = {b1, b1, b1, b1};
        const float* base = buf + (size_t)img * NC * HWs;

        for (int c = 0; c < NIN; ++c) {
            const float* plane = base + (size_t)c * HWs;
            float wk0[9], wk1[9];
#pragma unroll
            for (int kk = 0; kk < 9; ++kk) {
                wk0[kk] = wts[c * 9 + kk];
                wk1[kk] = wts[(NIN + c) * 9 + kk];
            }
#pragma unroll
            for (int i = 0; i < 4; ++i) {
                if (r0 + i < HH) {
#pragma unroll
                    for (int kr = 0; kr < 3; ++kr) {
                        const float* rowp = plane + ro[kr][i];
#pragma unroll
                        for (int kw = 0; kw < 3; ++kw) {
                            float vv = rowp[cw[kw]];
                            a0[i] = fmaf(vv, wk0[kr * 3 + kw], a0[i]);
                            a1[i] = fmaf(vv, wk1[kr * 3 + kw], a1[i]);
                        }
                    }
                }
            }
        }

        float* o0 = buf + (size_t)(img * NC + NIN) * HWs;
        float* o1 = o0 + HWs;
#pragma unroll
        for (int i = 0; i < 4; ++i) {
            if (r0 + i < HH) {
                size_t off = (size_t)(r0 + i) * WW + (size_t)w;
                o0[off] = fmaxf(a0[i], 0.f);
                o1[off] = fmaxf(a1[i], 0.f);
            }
        }
    }
}

// ---------------- fused cooperative kernel: 1 dispatch, 12 grid syncs ------
__global__ __launch_bounds__(256, 4) void msd_fused(Params p) {
    cg::grid_group grid = cg::this_grid();

    // bijective XCD swizzle for nblk = 1024 exactly: 128 consecutive virtual
    // blocks per XCD -> halo-sharing neighbors and layer(l)->layer(l+1)
    // producer/consumer rows stay within one XCD's L2.
    const int bid = ((blockIdx.x & 7) << 7) | (blockIdx.x >> 3);
    const int t = bid * 256 + threadIdx.x;

    // phase 0: copy x -> channel 0 (one float4 per thread: 262144 threads)
    {
        const int b = t >> 16;                 // HWs/4 = 65536 float4/batch
        const int r = t & 65535;
        const float4* src = (const float4*)(p.x + (size_t)b * HWs);
        float4* dst = (float4*)(p.out + (size_t)b * NC * HWs);
        dst[r] = src[r];
    }
    grid.sync();
    layer_body<1, 1>(p.w[0], p.bias, p.out, 0, t);
    grid.sync();
    layer_body<3, 2>(p.w[1], p.bias, p.out, 1, t);
    grid.sync();
    layer_body<5, 3>(p.w[2], p.bias, p.out, 2, t);
    grid.sync();
    layer_body<7, 4>(p.w[3], p.bias, p.out, 3, t);
    grid.sync();
    layer_body<9, 5>(p.w[4], p.bias, p.out, 4, t);
    grid.sync();
    layer_body<11, 6>(p.w[5], p.bias, p.out, 5, t);
    grid.sync();
    layer_body<13, 7>(p.w[6], p.bias, p.out, 6, t);
    grid.sync();
    layer_body<15, 8>(p.w[7], p.bias, p.out, 7, t);
    grid.sync();
    layer_body<17, 9>(p.w[8], p.bias, p.out, 8, t);
    grid.sync();
    layer_body<19, 10>(p.w[9], p.bias, p.out, 9, t);
    grid.sync();
    layer_body<21, 11>(p.w[10], p.bias, p.out, 10, t);
    grid.sync();
    layer_body<23, 12>(p.w[11], p.bias, p.out, 11, t);
}

// ---------------- fallback path (13 separate launches, same bodies) --------
__global__ __launch_bounds__(256) void copy_x_kernel(const float* __restrict__ x,
                                                     float* __restrict__ out) {
    int t = blockIdx.x * 256 + threadIdx.x;
    int b = t >> 16;
    int r = t & 65535;
    const float4* src = (const float4*)(x + (size_t)b * HWs);
    float4* dst = (float4*)(out + (size_t)b * NC * HWs);
    dst[r] = src[r];
}

template <int NIN, int DIL>
__global__ __launch_bounds__(256, 4) void msd_layer(const float* __restrict__ wts,
                                                    const float* __restrict__ bias,
                                                    float* __restrict__ buf,
                                                    int layer) {
    const int bid = ((blockIdx.x & 7) << 7) | (blockIdx.x >> 3);
    const int t = bid * 256 + threadIdx.x;
    layer_body<NIN, DIL>(wts, bias, buf, layer, t);
}

extern "C" void kernel_launch(void* const* d_in, const int* in_sizes, int n_in,
                              void* d_out, int out_size, void* d_ws, size_t ws_size,
                              hipStream_t stream) {
    Params p;
    p.x = (const float*)d_in[0];
    p.bias = (const float*)d_in[1];
    for (int i = 0; i < 12; ++i) p.w[i] = (const float*)d_in[2 + i];
    p.out = (float*)d_out;

    void* args[] = { (void*)&p };
    hipError_t err = hipLaunchCooperativeKernel((const void*)msd_fused,
                                                dim3(1024), dim3(256),
                                                args, 0, stream);
    if (err == hipSuccess) return;

    // fallback: same bodies, 13 dispatches (each layer is exactly 1024 blocks)
    copy_x_kernel<<<1024, 256, 0, stream>>>(p.x, p.out);
#define LAYER(i, nin, dil) \
    msd_layer<nin, dil><<<1024, 256, 0, stream>>>(p.w[i], p.bias, p.out, i)
    LAYER(0, 1, 1);
    LAYER(1, 3, 2);
    LAYER(2, 5, 3);
    LAYER(3, 7, 4);
    LAYER(4, 9, 5);
    LAYER(5, 11, 6);
    LAYER(6, 13, 7);
    LAYER(7, 15, 8);
    LAYER(8, 17, 9);
    LAYER(9, 19, 10);
    LAYER(10, 21, 11);
    LAYER(11, 23, 12);
#undef LAYER
}

// Round 5
// 518.326 us; speedup vs baseline: 3.4425x; 3.4425x over previous
//
#include <hip/hip_runtime.h>

#define HH 512
#define WW 512
#define NC 25              // final channel count: 1 + 12*2
#define HWs (HH * WW)

__device__ __forceinline__ int refl(int p, int n) {
    p = (p < 0) ? -p : p;
    p = (p >= n) ? (2 * n - 2 - p) : p;
    return p;
}

__global__ __launch_bounds__(256) void copy_x_kernel(const float* __restrict__ x,
                                                     float* __restrict__ out) {
    int t = blockIdx.x * 256 + threadIdx.x;   // NB*HWs/4 = 262144 threads
    int b = t >> 16;                          // HWs/4 = 65536 float4 per batch
    int r = t & 65535;
    const float4* src = (const float4*)(x + (size_t)b * HWs);
    float4* dst = (float4*)(out + (size_t)b * NC * HWs);
    dst[r] = src[r];
}

// R5: latency/TLP-bound per R4 counters (VALUBusy 5.8% fused => ~100us real
// VALU work; HBM 3%; occupancy grid-capped at 16/32 waves). 2-row scheme:
// thread owns rows {h, h+d}, loads 4 rows {h-d..h+2d} x 3 col-taps = 12
// dword loads / 2 px. DM ~= 250-256 for every DIL -> ~2048 blocks/layer =
// 8 blocks/CU = 32 waves/CU (FULL occupancy, 2x R3). VGPR ~52 <= 64 budget,
// enforced by __launch_bounds__(256,8). 1-deep channel prefetch retained.
template <int NIN, int DIL>
__global__ __launch_bounds__(256, 8) void msd_layer(const float* __restrict__ wts,
                                                    const float* __restrict__ bias,
                                                    float* __restrict__ buf,
                                                    int layer) {
    constexpr int M2 = 512 / (2 * DIL);
    constexpr int DM = DIL * M2;          // row-bases per image (250..256)
    constexpr int SPAN = 2 * DM;          // rows covered by main path
    constexpr int RT = 512 - SPAN;        // tail rows (0..12)
    constexpr int TCH = (RT + 3) / 4;     // tail chunks of 4 rows
    constexpr int IMT = 512 * DM;         // main threads per image
    constexpr int NMAIN = 4 * IMT;

    // ---- bijective chunked XCD swizzle (MI355X: 8 XCDs, round-robin) ----
    int bid = blockIdx.x;
    {
        const int nblk = gridDim.x;
        const int q = nblk >> 3, r = nblk & 7;
        const int xcd = bid & 7, idx = bid >> 3;
        bid = (xcd < r ? xcd * (q + 1) : r * (q + 1) + (xcd - r) * q) + idx;
    }
    const int t = bid * 256 + threadIdx.x;

    const float b0 = bias[2 * layer];
    const float b1 = bias[2 * layer + 1];

    if (t < NMAIN) {
        const int img = t / IMT;                       // uniform per block
        const int u = t - img * IMT;
        const int bi = __builtin_amdgcn_readfirstlane(u >> 9);   // base index
        const int w = u & 511;                         // per-lane column
        const int k = bi / DIL, j = bi - k * DIL;
        const int h = 2 * DIL * k + j;                 // base output row (scalar)

        int rowoff[4];                                 // rows h+(r-1)*d, scalar
#pragma unroll
        for (int r = 0; r < 4; ++r) rowoff[r] = refl(h + (r - 1) * DIL, HH) * WW;
        int cw[3];                                     // per-lane col taps
#pragma unroll
        for (int q = 0; q < 3; ++q) cw[q] = refl(w + (q - 1) * DIL, WW);

        float a0[2] = {b0, b0};
        float a1[2] = {b1, b1};
        const float* base = buf + (size_t)img * NC * HWs;

        // preload channel 0 pixel block
        float v[4][3];
#pragma unroll
        for (int r = 0; r < 4; ++r) {
            const float* rowp = base + rowoff[r];
#pragma unroll
            for (int q = 0; q < 3; ++q) v[r][q] = rowp[cw[q]];
        }

#pragma unroll
        for (int c = 0; c < NIN; ++c) {
            // ---- prefetch channel c+1 pixels while FMAs of channel c run ----
            float vn[4][3];
            if (c + 1 < NIN) {
                const float* pn = base + (size_t)(c + 1) * HWs;
#pragma unroll
                for (int r = 0; r < 4; ++r) {
                    const float* rowp = pn + rowoff[r];
#pragma unroll
                    for (int q = 0; q < 3; ++q) vn[r][q] = rowp[cw[q]];
                }
            }

            float wk0[9], wk1[9];
#pragma unroll
            for (int kk = 0; kk < 9; ++kk) {
                wk0[kk] = wts[c * 9 + kk];             // uniform -> s_load
                wk1[kk] = wts[(NIN + c) * 9 + kk];
            }

            // ---- 36 FMAs on the resident channel ----
#pragma unroll
            for (int al = 0; al < 2; ++al)
#pragma unroll
                for (int kr = 0; kr < 3; ++kr)
#pragma unroll
                    for (int kw = 0; kw < 3; ++kw) {
                        float vv = v[al + kr][kw];
                        a0[al] = fmaf(vv, wk0[kr * 3 + kw], a0[al]);
                        a1[al] = fmaf(vv, wk1[kr * 3 + kw], a1[al]);
                    }

            // ---- rotate (SSA-renamed away under full unroll) ----
            if (c + 1 < NIN) {
#pragma unroll
                for (int r = 0; r < 4; ++r)
#pragma unroll
                    for (int q = 0; q < 3; ++q) v[r][q] = vn[r][q];
            }
        }

        float* o0 = buf + (size_t)(img * NC + NIN) * HWs;
        float* o1 = o0 + HWs;
#pragma unroll
        for (int al = 0; al < 2; ++al) {
            size_t off = (size_t)(h + al * DIL) * WW + (size_t)w;
            o0[off] = fmaxf(a0[al], 0.f);
            o1[off] = fmaxf(a1[al], 0.f);
        }
    } else if (RT > 0) {
        const int t2 = t - NMAIN;
        constexpr int PIT = 512 * TCH;
        const int img = t2 / PIT;
        const int u = t2 - img * PIT;
        const int s = __builtin_amdgcn_readfirstlane(u >> 9);
        const int w = u & 511;
        const int r0 = SPAN + 4 * s;

        int cw[3];
#pragma unroll
        for (int q = 0; q < 3; ++q) cw[q] = refl(w + (q - 1) * DIL, WW);
        int ro[3][4];
#pragma unroll
        for (int kr = 0; kr < 3; ++kr)
#pragma unroll
            for (int i = 0; i < 4; ++i)
                ro[kr][i] = refl(r0 + i + (kr - 1) * DIL, HH) * WW;

        float a0[4] = {b0, b0, b0, b0};
        float a1[4] = {b1, b1, b1, b1};
        const float* base = buf + (size_t)img * NC * HWs;

        for (int c = 0; c < NIN; ++c) {
            const float* plane = base + (size_t)c * HWs;
            float wk0[9], wk1[9];
#pragma unroll
            for (int kk = 0; kk < 9; ++kk) {
                wk0[kk] = wts[c * 9 + kk];
                wk1[kk] = wts[(NIN + c) * 9 + kk];
            }
#pragma unroll
            for (int i = 0; i < 4; ++i) {
                if (r0 + i < HH) {
#pragma unroll
                    for (int kr = 0; kr < 3; ++kr) {
                        const float* rowp = plane + ro[kr][i];
#pragma unroll
                        for (int kw = 0; kw < 3; ++kw) {
                            float vv = rowp[cw[kw]];
                            a0[i] = fmaf(vv, wk0[kr * 3 + kw], a0[i]);
                            a1[i] = fmaf(vv, wk1[kr * 3 + kw], a1[i]);
                        }
                    }
                }
            }
        }

        float* o0 = buf + (size_t)(img * NC + NIN) * HWs;
        float* o1 = o0 + HWs;
#pragma unroll
        for (int i = 0; i < 4; ++i) {
            if (r0 + i < HH) {
                size_t off = (size_t)(r0 + i) * WW + (size_t)w;
                o0[off] = fmaxf(a0[i], 0.f);
                o1[off] = fmaxf(a1[i], 0.f);
            }
        }
    }
}

extern "C" void kernel_launch(void* const* d_in, const int* in_sizes, int n_in,
                              void* d_out, int out_size, void* d_ws, size_t ws_size,
                              hipStream_t stream) {
    const float* x = (const float*)d_in[0];
    const float* bias = (const float*)d_in[1];
    float* out = (float*)d_out;

    copy_x_kernel<<<1024, 256, 0, stream>>>(x, out);

// blocks = (main + tail threads)/256 = 8*DM + 8*TCH  (2-row scheme, ~2048)
#define GBLK(dil) (8 * ((dil) * (512 / (2 * (dil)))) \
                 + 8 * (((512 - 2 * ((dil) * (512 / (2 * (dil))))) + 3) / 4))
#define LAYER(i, nin, dil) \
    msd_layer<nin, dil><<<GBLK(dil), 256, 0, stream>>>((const float*)d_in[2 + i], bias, out, i)

    LAYER(0, 1, 1);
    LAYER(1, 3, 2);
    LAYER(2, 5, 3);
    LAYER(3, 7, 4);
    LAYER(4, 9, 5);
    LAYER(5, 11, 6);
    LAYER(6, 13, 7);
    LAYER(7, 15, 8);
    LAYER(8, 17, 9);
    LAYER(9, 19, 10);
    LAYER(10, 21, 11);
    LAYER(11, 23, 12);
#undef LAYER
#undef GBLK
}

// Round 6
// 377.600 us; speedup vs baseline: 4.7255x; 1.3727x over previous
//
#include <hip/hip_runtime.h>

#define HH 512
#define WW 512
#define NC 25              // final channel count: 1 + 12*2
#define HWs (HH * WW)

__device__ __forceinline__ int refl(int p, int n) {
    p = (p < 0) ? -p : p;
    p = (p >= n) ? (2 * n - 2 - p) : p;
    return p;
}

__global__ __launch_bounds__(256) void copy_x_kernel(const float* __restrict__ x,
                                                     float* __restrict__ out) {
    int t = blockIdx.x * 256 + threadIdx.x;   // NB*HWs/4 = 262144 threads
    int b = t >> 16;                          // HWs/4 = 65536 float4 per batch
    int r = t & 65535;
    const float4* src = (const float4*)(x + (size_t)b * HWs);
    float4* dst = (float4*)(out + (size_t)b * NC * HWs);
    dst[r] = src[r];
}

// R6: R5's 2-row scheme unchanged, but __launch_bounds__(256,4).
// R5's (256,8) forced a 32-VGPR cap -> the ~46-VGPR live set spilled to
// scratch -> occupancy 9.4%, latency-serialized, 518us. Empirically on this
// toolchain: arg=8 -> 32-VGPR cap, arg=4 -> 64-VGPR cap. The 2-row body fits
// 64 without spills, and 64 VGPR allows 8 waves/EU = 32 waves/CU with the
// ~2032-block grid -> full-occupancy latency hiding.
// Thread owns rows {h, h+d}; loads 4 rows {h-d..h+2d} x 3 col-taps = 12
// dword loads / 2 px; 1-deep channel prefetch; lane = consecutive col.
template <int NIN, int DIL>
__global__ __launch_bounds__(256, 4) void msd_layer(const float* __restrict__ wts,
                                                    const float* __restrict__ bias,
                                                    float* __restrict__ buf,
                                                    int layer) {
    constexpr int M2 = 512 / (2 * DIL);
    constexpr int DM = DIL * M2;          // row-bases per image (250..256)
    constexpr int SPAN = 2 * DM;          // rows covered by main path
    constexpr int RT = 512 - SPAN;        // tail rows (0..12)
    constexpr int TCH = (RT + 3) / 4;     // tail chunks of 4 rows
    constexpr int IMT = 512 * DM;         // main threads per image
    constexpr int NMAIN = 4 * IMT;

    // ---- bijective chunked XCD swizzle (MI355X: 8 XCDs, round-robin) ----
    int bid = blockIdx.x;
    {
        const int nblk = gridDim.x;
        const int q = nblk >> 3, r = nblk & 7;
        const int xcd = bid & 7, idx = bid >> 3;
        bid = (xcd < r ? xcd * (q + 1) : r * (q + 1) + (xcd - r) * q) + idx;
    }
    const int t = bid * 256 + threadIdx.x;

    const float b0 = bias[2 * layer];
    const float b1 = bias[2 * layer + 1];

    if (t < NMAIN) {
        const int img = t / IMT;                       // uniform per block
        const int u = t - img * IMT;
        const int bi = __builtin_amdgcn_readfirstlane(u >> 9);   // base index
        const int w = u & 511;                         // per-lane column
        const int k = bi / DIL, j = bi - k * DIL;
        const int h = 2 * DIL * k + j;                 // base output row (scalar)

        int rowoff[4];                                 // rows h+(r-1)*d, scalar
#pragma unroll
        for (int r = 0; r < 4; ++r) rowoff[r] = refl(h + (r - 1) * DIL, HH) * WW;
        int cw[3];                                     // per-lane col taps
#pragma unroll
        for (int q = 0; q < 3; ++q) cw[q] = refl(w + (q - 1) * DIL, WW);

        float a0[2] = {b0, b0};
        float a1[2] = {b1, b1};
        const float* base = buf + (size_t)img * NC * HWs;

        // preload channel 0 pixel block
        float v[4][3];
#pragma unroll
        for (int r = 0; r < 4; ++r) {
            const float* rowp = base + rowoff[r];
#pragma unroll
            for (int q = 0; q < 3; ++q) v[r][q] = rowp[cw[q]];
        }

#pragma unroll
        for (int c = 0; c < NIN; ++c) {
            // ---- prefetch channel c+1 pixels while FMAs of channel c run ----
            float vn[4][3];
            if (c + 1 < NIN) {
                const float* pn = base + (size_t)(c + 1) * HWs;
#pragma unroll
                for (int r = 0; r < 4; ++r) {
                    const float* rowp = pn + rowoff[r];
#pragma unroll
                    for (int q = 0; q < 3; ++q) vn[r][q] = rowp[cw[q]];
                }
            }

            float wk0[9], wk1[9];
#pragma unroll
            for (int kk = 0; kk < 9; ++kk) {
                wk0[kk] = wts[c * 9 + kk];             // uniform -> s_load
                wk1[kk] = wts[(NIN + c) * 9 + kk];
            }

            // ---- 36 FMAs on the resident channel ----
#pragma unroll
            for (int al = 0; al < 2; ++al)
#pragma unroll
                for (int kr = 0; kr < 3; ++kr)
#pragma unroll
                    for (int kw = 0; kw < 3; ++kw) {
                        float vv = v[al + kr][kw];
                        a0[al] = fmaf(vv, wk0[kr * 3 + kw], a0[al]);
                        a1[al] = fmaf(vv, wk1[kr * 3 + kw], a1[al]);
                    }

            // ---- rotate (SSA-renamed away under full unroll) ----
            if (c + 1 < NIN) {
#pragma unroll
                for (int r = 0; r < 4; ++r)
#pragma unroll
                    for (int q = 0; q < 3; ++q) v[r][q] = vn[r][q];
            }
        }

        float* o0 = buf + (size_t)(img * NC + NIN) * HWs;
        float* o1 = o0 + HWs;
#pragma unroll
        for (int al = 0; al < 2; ++al) {
            size_t off = (size_t)(h + al * DIL) * WW + (size_t)w;
            o0[off] = fmaxf(a0[al], 0.f);
            o1[off] = fmaxf(a1[al], 0.f);
        }
    } else if (RT > 0) {
        const int t2 = t - NMAIN;
        constexpr int PIT = 512 * TCH;
        const int img = t2 / PIT;
        const int u = t2 - img * PIT;
        const int s = __builtin_amdgcn_readfirstlane(u >> 9);
        const int w = u & 511;
        const int r0 = SPAN + 4 * s;

        int cw[3];
#pragma unroll
        for (int q = 0; q < 3; ++q) cw[q] = refl(w + (q - 1) * DIL, WW);
        int ro[3][4];
#pragma unroll
        for (int kr = 0; kr < 3; ++kr)
#pragma unroll
            for (int i = 0; i < 4; ++i)
                ro[kr][i] = refl(r0 + i + (kr - 1) * DIL, HH) * WW;

        float a0[4] = {b0, b0, b0, b0};
        float a1[4] = {b1, b1, b1, b1};
        const float* base = buf + (size_t)img * NC * HWs;

        for (int c = 0; c < NIN; ++c) {
            const float* plane = base + (size_t)c * HWs;
            float wk0[9], wk1[9];
#pragma unroll
            for (int kk = 0; kk < 9; ++kk) {
                wk0[kk] = wts[c * 9 + kk];
                wk1[kk] = wts[(NIN + c) * 9 + kk];
            }
#pragma unroll
            for (int i = 0; i < 4; ++i) {
                if (r0 + i < HH) {
#pragma unroll
                    for (int kr = 0; kr < 3; ++kr) {
                        const float* rowp = plane + ro[kr][i];
#pragma unroll
                        for (int kw = 0; kw < 3; ++kw) {
                            float vv = rowp[cw[kw]];
                            a0[i] = fmaf(vv, wk0[kr * 3 + kw], a0[i]);
                            a1[i] = fmaf(vv, wk1[kr * 3 + kw], a1[i]);
                        }
                    }
                }
            }
        }

        float* o0 = buf + (size_t)(img * NC + NIN) * HWs;
        float* o1 = o0 + HWs;
#pragma unroll
        for (int i = 0; i < 4; ++i) {
            if (r0 + i < HH) {
                size_t off = (size_t)(r0 + i) * WW + (size_t)w;
                o0[off] = fmaxf(a0[i], 0.f);
                o1[off] = fmaxf(a1[i], 0.f);
            }
        }
    }
}

extern "C" void kernel_launch(void* const* d_in, const int* in_sizes, int n_in,
                              void* d_out, int out_size, void* d_ws, size_t ws_size,
                              hipStream_t stream) {
    const float* x = (const float*)d_in[0];
    const float* bias = (const float*)d_in[1];
    float* out = (float*)d_out;

    copy_x_kernel<<<1024, 256, 0, stream>>>(x, out);

// blocks = (main + tail threads)/256 = 8*DM + 8*TCH  (2-row scheme, ~2048)
#define GBLK(dil) (8 * ((dil) * (512 / (2 * (dil)))) \
                 + 8 * (((512 - 2 * ((dil) * (512 / (2 * (dil))))) + 3) / 4))
#define LAYER(i, nin, dil) \
    msd_layer<nin, dil><<<GBLK(dil), 256, 0, stream>>>((const float*)d_in[2 + i], bias, out, i)

    LAYER(0, 1, 1);
    LAYER(1, 3, 2);
    LAYER(2, 5, 3);
    LAYER(3, 7, 4);
    LAYER(4, 9, 5);
    LAYER(5, 11, 6);
    LAYER(6, 13, 7);
    LAYER(7, 15, 8);
    LAYER(8, 17, 9);
    LAYER(9, 19, 10);
    LAYER(10, 21, 11);
    LAYER(11, 23, 12);
#undef LAYER
#undef GBLK
}

// Round 7
// 362.643 us; speedup vs baseline: 4.9204x; 1.0412x over previous
//
#include <hip/hip_runtime.h>

#define HH 512
#define WW 512
#define NC 25              // final channel count: 1 + 12*2
#define HWs (HH * WW)

__device__ __forceinline__ int refl(int p, int n) {
    p = (p < 0) ? -p : p;
    p = (p >= n) ? (2 * n - 2 - p) : p;
    return p;
}

__global__ __launch_bounds__(256) void copy_x_kernel(const float* __restrict__ x,
                                                     float* __restrict__ out) {
    int t = blockIdx.x * 256 + threadIdx.x;   // NB*HWs/4 = 262144 threads
    int b = t >> 16;                          // HWs/4 = 65536 float4 per batch
    int r = t & 65535;
    const float4* src = (const float4*)(x + (size_t)b * HWs);
    float4* dst = (float4*)(out + (size_t)b * NC * HWs);
    dst[r] = src[r];
}

// R7: phase-stagger theory. Session ledger ranks configs by execution phase
// alignment (R4 lockstep 1784 > R2 barriers 453 > R3 exact-grid 448 > R6
// 7.9-gen 377 > R1 5.3-gen 365), not by instr count / occupancy / traffic.
// Diagnosis: all blocks sweeping channel planes in the same order makes the
// chip issue synchronized load bursts at one plane region -> L2/L3 demand
// spikes + queueing. Fixes:
//  (1) per-block channel rotation: block starts at c0 = bid % NIN and wraps
//      -> co-resident blocks read different planes at any instant (fp-sum
//      reorder is tolerance-safe).
//  (2) ping-pong vA/vB channel buffers (unroll-by-2): no rotate movs,
//      ~45 VGPR live set, fits the 64-VGPR (256,4) budget with margin.
// Geometry = R1's best-measured: 3-row dilation-symmetry scheme, 1368-ish
// blocks (5.3 gens/CU -> naturally staggered), XCD swizzle, 13 dispatches.
template <int NIN, int DIL>
__global__ __launch_bounds__(256, 4) void msd_layer(const float* __restrict__ wts,
                                                    const float* __restrict__ bias,
                                                    float* __restrict__ buf,
                                                    int layer) {
    constexpr int M3 = 512 / (3 * DIL);
    constexpr int DM = DIL * M3;          // row-bases per image
    constexpr int SPAN = 3 * DM;          // rows covered by main path
    constexpr int RT = 512 - SPAN;        // tail rows (0..26)
    constexpr int TCH = (RT + 3) / 4;     // tail chunks of 4 rows
    constexpr int IMT = 512 * DM;         // main threads per image
    constexpr int NMAIN = 4 * IMT;

    // ---- bijective chunked XCD swizzle (MI355X: 8 XCDs, round-robin) ----
    int bid = blockIdx.x;
    {
        const int nblk = gridDim.x;
        const int q = nblk >> 3, r = nblk & 7;
        const int xcd = bid & 7, idx = bid >> 3;
        bid = (xcd < r ? xcd * (q + 1) : r * (q + 1) + (xcd - r) * q) + idx;
    }
    const int t = bid * 256 + threadIdx.x;

    const float b0 = bias[2 * layer];
    const float b1 = bias[2 * layer + 1];

    if (t < NMAIN) {
        const int img = t / IMT;                       // uniform per block
        const int u = t - img * IMT;
        const int bi = __builtin_amdgcn_readfirstlane(u >> 9);   // base index
        const int w = u & 511;                         // per-lane column
        const int k = bi / DIL, j = bi - k * DIL;
        const int h = 3 * DIL * k + j;                 // base output row (scalar)

        int rowoff[5];                                 // rows h+(r-1)*d, scalar
#pragma unroll
        for (int r = 0; r < 5; ++r) rowoff[r] = refl(h + (r - 1) * DIL, HH) * WW;
        int cw[3];                                     // per-lane col taps
#pragma unroll
        for (int q = 0; q < 3; ++q) cw[q] = refl(w + (q - 1) * DIL, WW);

        float a0[3] = {b0, b0, b0};
        float a1[3] = {b1, b1, b1};
        const float* base = buf + (size_t)img * NC * HWs;

        // per-block channel-rotation start (scalar; NIN is compile-time)
        const int c0 = bid - (bid / NIN) * NIN;        // bid % NIN

        float vA[5][3], vB[5][3];

        auto LD = [&](float (&v)[5][3], int c) {
            const float* plane = base + (size_t)c * HWs;
#pragma unroll
            for (int r = 0; r < 5; ++r) {
                const float* rowp = plane + rowoff[r];
#pragma unroll
                for (int q = 0; q < 3; ++q) v[r][q] = rowp[cw[q]];
            }
        };
        auto FM = [&](const float (&v)[5][3], int c) {
            float wk0[9], wk1[9];
#pragma unroll
            for (int kk = 0; kk < 9; ++kk) {
                wk0[kk] = wts[c * 9 + kk];             // uniform -> s_load
                wk1[kk] = wts[(NIN + c) * 9 + kk];
            }
#pragma unroll
            for (int al = 0; al < 3; ++al)
#pragma unroll
                for (int kr = 0; kr < 3; ++kr)
#pragma unroll
                    for (int kw = 0; kw < 3; ++kw) {
                        float vv = v[al + kr][kw];
                        a0[al] = fmaf(vv, wk0[kr * 3 + kw], a0[al]);
                        a1[al] = fmaf(vv, wk1[kr * 3 + kw], a1[al]);
                    }
        };

        LD(vA, c0);
#pragma unroll
        for (int i = 0; i < NIN; i += 2) {
            int cA = c0 + i;     cA -= (cA >= NIN) ? NIN : 0;
            int cB = c0 + i + 1; cB -= (cB >= NIN) ? NIN : 0;
            if (i + 1 < NIN) LD(vB, cB);               // issue B loads
            FM(vA, cA);                                // compute A
            if (i + 1 >= NIN) break;
            int cN = c0 + i + 2; cN -= (cN >= NIN) ? NIN : 0;
            if (i + 2 < NIN) LD(vA, cN);               // issue A loads
            FM(vB, cB);                                // compute B
        }

        float* o0 = buf + (size_t)(img * NC + NIN) * HWs;
        float* o1 = o0 + HWs;
#pragma unroll
        for (int al = 0; al < 3; ++al) {
            size_t off = (size_t)(h + al * DIL) * WW + (size_t)w;
            o0[off] = fmaxf(a0[al], 0.f);
            o1[off] = fmaxf(a1[al], 0.f);
        }
    } else if (RT > 0) {
        const int t2 = t - NMAIN;
        constexpr int PIT = 512 * TCH;
        const int img = t2 / PIT;
        const int u = t2 - img * PIT;
        const int s = __builtin_amdgcn_readfirstlane(u >> 9);
        const int w = u & 511;
        const int r0 = SPAN + 4 * s;

        int cw[3];
#pragma unroll
        for (int q = 0; q < 3; ++q) cw[q] = refl(w + (q - 1) * DIL, WW);
        int ro[3][4];
#pragma unroll
        for (int kr = 0; kr < 3; ++kr)
#pragma unroll
            for (int i = 0; i < 4; ++i)
                ro[kr][i] = refl(r0 + i + (kr - 1) * DIL, HH) * WW;

        float a0[4] = {b0, b0, b0, b0};
        float a1[4] = {b1, b1, b1, b1};
        const float* base = buf + (size_t)img * NC * HWs;

        for (int c = 0; c < NIN; ++c) {
            const float* plane = base + (size_t)c * HWs;
            float wk0[9], wk1[9];
#pragma unroll
            for (int kk = 0; kk < 9; ++kk) {
                wk0[kk] = wts[c * 9 + kk];
                wk1[kk] = wts[(NIN + c) * 9 + kk];
            }
#pragma unroll
            for (int i = 0; i < 4; ++i) {
                if (r0 + i < HH) {
#pragma unroll
                    for (int kr = 0; kr < 3; ++kr) {
                        const float* rowp = plane + ro[kr][i];
#pragma unroll
                        for (int kw = 0; kw < 3; ++kw) {
                            float vv = rowp[cw[kw]];
                            a0[i] = fmaf(vv, wk0[kr * 3 + kw], a0[i]);
                            a1[i] = fmaf(vv, wk1[kr * 3 + kw], a1[i]);
                        }
                    }
                }
            }
        }

        float* o0 = buf + (size_t)(img * NC + NIN) * HWs;
        float* o1 = o0 + HWs;
#pragma unroll
        for (int i = 0; i < 4; ++i) {
            if (r0 + i < HH) {
                size_t off = (size_t)(r0 + i) * WW + (size_t)w;
                o0[off] = fmaxf(a0[i], 0.f);
                o1[off] = fmaxf(a1[i], 0.f);
            }
        }
    }
}

extern "C" void kernel_launch(void* const* d_in, const int* in_sizes, int n_in,
                              void* d_out, int out_size, void* d_ws, size_t ws_size,
                              hipStream_t stream) {
    const float* x = (const float*)d_in[0];
    const float* bias = (const float*)d_in[1];
    float* out = (float*)d_out;

    copy_x_kernel<<<1024, 256, 0, stream>>>(x, out);

// blocks = (main threads + tail threads) / 256 = 8*DM + 8*TCH  (3-row scheme)
#define GBLK(dil) (8 * ((512 / (3 * (dil))) * (dil)) \
                 + 8 * (((512 - 3 * ((512 / (3 * (dil))) * (dil))) + 3) / 4))
#define LAYER(i, nin, dil) \
    msd_layer<nin, dil><<<GBLK(dil), 256, 0, stream>>>((const float*)d_in[2 + i], bias, out, i)

    LAYER(0, 1, 1);
    LAYER(1, 3, 2);
    LAYER(2, 5, 3);
    LAYER(3, 7, 4);
    LAYER(4, 9, 5);
    LAYER(5, 11, 6);
    LAYER(6, 13, 7);
    LAYER(7, 15, 8);
    LAYER(8, 17, 9);
    LAYER(9, 19, 10);
    LAYER(10, 21, 11);
    LAYER(11, 23, 12);
#undef LAYER
#undef GBLK
}

// Round 8
// 331.872 us; speedup vs baseline: 5.3767x; 1.0927x over previous
//
#include <hip/hip_runtime.h>

#define HH 512
#define WW 512
#define NC 25              // final channel count: 1 + 12*2
#define HWs (HH * WW)

__device__ __forceinline__ int refl(int p, int n) {
    p = (p < 0) ? -p : p;
    p = (p >= n) ? (2 * n - 2 - p) : p;
    return p;
}

__global__ __launch_bounds__(256) void copy_x_kernel(const float* __restrict__ x,
                                                     float* __restrict__ out) {
    int t = blockIdx.x * 256 + threadIdx.x;   // NB*HWs/4 = 262144 threads
    int b = t >> 16;                          // HWs/4 = 65536 float4 per batch
    int r = t & 65535;
    const float4* src = (const float4*)(x + (size_t)b * HWs);
    float4* dst = (float4*)(out + (size_t)b * NC * HWs);
    dst[r] = src[r];
}

// R8: traffic-reduction round. Ledger evidence: TLP 12->32 waves/CU flat
// (R0/R1/R6) => the L2-miss (L3-served) line-throughput is saturated; only
// fewer line-fetches chip-wide can help. K-row scheme fetches (K+2)/K rows
// per output row: K=3 -> 1.67x, K=6 -> 1.33x (-20% traffic, -10% loads/px).
// 6-row scheme: thread owns rows h+al*DIL (al=0..5); loads 8 rows
// {h-d..h+6d} x 3 col-taps = 24 dword loads / 6 px. Live VGPR ~75 ->
// __launch_bounds__(256,3) (85-VGPR cap); ~688-720 blocks/layer = ~2.7
// blocks/CU (~11 waves/CU — proven sufficient by R6's flat TLP result).
// Keeps: XCD swizzle, per-block channel rotation, ping-pong A/B buffers.
template <int NIN, int DIL>
__global__ __launch_bounds__(256, 3) void msd_layer(const float* __restrict__ wts,
                                                    const float* __restrict__ bias,
                                                    float* __restrict__ buf,
                                                    int layer) {
    constexpr int M6 = 512 / (6 * DIL);
    constexpr int DM = DIL * M6;          // row-bases per image
    constexpr int SPAN = 6 * DM;          // rows covered by main path
    constexpr int RT = 512 - SPAN;        // tail rows (0..50)
    constexpr int TCH = (RT + 3) / 4;     // tail chunks of 4 rows
    constexpr int IMT = 512 * DM;         // main threads per image
    constexpr int NMAIN = 4 * IMT;

    // ---- bijective chunked XCD swizzle (MI355X: 8 XCDs, round-robin) ----
    int bid = blockIdx.x;
    {
        const int nblk = gridDim.x;
        const int q = nblk >> 3, r = nblk & 7;
        const int xcd = bid & 7, idx = bid >> 3;
        bid = (xcd < r ? xcd * (q + 1) : r * (q + 1) + (xcd - r) * q) + idx;
    }
    const int t = bid * 256 + threadIdx.x;

    const float b0 = bias[2 * layer];
    const float b1 = bias[2 * layer + 1];

    if (t < NMAIN) {
        const int img = t / IMT;                       // uniform per block
        const int u = t - img * IMT;
        const int bi = __builtin_amdgcn_readfirstlane(u >> 9);   // base index
        const int w = u & 511;                         // per-lane column
        const int k = bi / DIL, j = bi - k * DIL;
        const int h = 6 * DIL * k + j;                 // base output row (scalar)

        int rowoff[8];                                 // rows h+(r-1)*d, scalar
#pragma unroll
        for (int r = 0; r < 8; ++r) rowoff[r] = refl(h + (r - 1) * DIL, HH) * WW;
        int cw[3];                                     // per-lane col taps
#pragma unroll
        for (int q = 0; q < 3; ++q) cw[q] = refl(w + (q - 1) * DIL, WW);

        float a0[6], a1[6];
#pragma unroll
        for (int al = 0; al < 6; ++al) { a0[al] = b0; a1[al] = b1; }
        const float* base = buf + (size_t)img * NC * HWs;

        // per-block channel-rotation start (scalar; NIN is compile-time)
        const int c0 = bid - (bid / NIN) * NIN;        // bid % NIN

        float vA[8][3], vB[8][3];

        auto LD = [&](float (&v)[8][3], int c) {
            const float* plane = base + (size_t)c * HWs;
#pragma unroll
            for (int r = 0; r < 8; ++r) {
                const float* rowp = plane + rowoff[r];
#pragma unroll
                for (int q = 0; q < 3; ++q) v[r][q] = rowp[cw[q]];
            }
        };
        auto FM = [&](const float (&v)[8][3], int c) {
            float wk0[9], wk1[9];
#pragma unroll
            for (int kk = 0; kk < 9; ++kk) {
                wk0[kk] = wts[c * 9 + kk];             // uniform -> s_load
                wk1[kk] = wts[(NIN + c) * 9 + kk];
            }
#pragma unroll
            for (int al = 0; al < 6; ++al)
#pragma unroll
                for (int kr = 0; kr < 3; ++kr)
#pragma unroll
                    for (int kw = 0; kw < 3; ++kw) {
                        float vv = v[al + kr][kw];
                        a0[al] = fmaf(vv, wk0[kr * 3 + kw], a0[al]);
                        a1[al] = fmaf(vv, wk1[kr * 3 + kw], a1[al]);
                    }
        };

        LD(vA, c0);
#pragma unroll
        for (int i = 0; i < NIN; i += 2) {
            int cA = c0 + i;     cA -= (cA >= NIN) ? NIN : 0;
            int cB = c0 + i + 1; cB -= (cB >= NIN) ? NIN : 0;
            if (i + 1 < NIN) LD(vB, cB);               // issue B loads
            FM(vA, cA);                                // compute A
            if (i + 1 >= NIN) break;
            int cN = c0 + i + 2; cN -= (cN >= NIN) ? NIN : 0;
            if (i + 2 < NIN) LD(vA, cN);               // issue A loads
            FM(vB, cB);                                // compute B
        }

        float* o0 = buf + (size_t)(img * NC + NIN) * HWs;
        float* o1 = o0 + HWs;
#pragma unroll
        for (int al = 0; al < 6; ++al) {
            size_t off = (size_t)(h + al * DIL) * WW + (size_t)w;
            o0[off] = fmaxf(a0[al], 0.f);
            o1[off] = fmaxf(a1[al], 0.f);
        }
    } else if (RT > 0) {
        const int t2 = t - NMAIN;
        constexpr int PIT = 512 * TCH;
        const int img = t2 / PIT;
        const int u = t2 - img * PIT;
        const int s = __builtin_amdgcn_readfirstlane(u >> 9);
        const int w = u & 511;
        const int r0 = SPAN + 4 * s;

        int cw[3];
#pragma unroll
        for (int q = 0; q < 3; ++q) cw[q] = refl(w + (q - 1) * DIL, WW);
        int ro[3][4];
#pragma unroll
        for (int kr = 0; kr < 3; ++kr)
#pragma unroll
            for (int i = 0; i < 4; ++i)
                ro[kr][i] = refl(r0 + i + (kr - 1) * DIL, HH) * WW;

        float a0[4] = {b0, b0, b0, b0};
        float a1[4] = {b1, b1, b1, b1};
        const float* base = buf + (size_t)img * NC * HWs;

        for (int c = 0; c < NIN; ++c) {
            const float* plane = base + (size_t)c * HWs;
            float wk0[9], wk1[9];
#pragma unroll
            for (int kk = 0; kk < 9; ++kk) {
                wk0[kk] = wts[c * 9 + kk];
                wk1[kk] = wts[(NIN + c) * 9 + kk];
            }
#pragma unroll
            for (int i = 0; i < 4; ++i) {
                if (r0 + i < HH) {
#pragma unroll
                    for (int kr = 0; kr < 3; ++kr) {
                        const float* rowp = plane + ro[kr][i];
#pragma unroll
                        for (int kw = 0; kw < 3; ++kw) {
                            float vv = rowp[cw[kw]];
                            a0[i] = fmaf(vv, wk0[kr * 3 + kw], a0[i]);
                            a1[i] = fmaf(vv, wk1[kr * 3 + kw], a1[i]);
                        }
                    }
                }
            }
        }

        float* o0 = buf + (size_t)(img * NC + NIN) * HWs;
        float* o1 = o0 + HWs;
#pragma unroll
        for (int i = 0; i < 4; ++i) {
            if (r0 + i < HH) {
                size_t off = (size_t)(r0 + i) * WW + (size_t)w;
                o0[off] = fmaxf(a0[i], 0.f);
                o1[off] = fmaxf(a1[i], 0.f);
            }
        }
    }
}

extern "C" void kernel_launch(void* const* d_in, const int* in_sizes, int n_in,
                              void* d_out, int out_size, void* d_ws, size_t ws_size,
                              hipStream_t stream) {
    const float* x = (const float*)d_in[0];
    const float* bias = (const float*)d_in[1];
    float* out = (float*)d_out;

    copy_x_kernel<<<1024, 256, 0, stream>>>(x, out);

// blocks = (main + tail threads)/256 = 8*DM + 8*TCH  (6-row scheme)
#define GBLK(dil) (8 * ((dil) * (512 / (6 * (dil)))) \
                 + 8 * (((512 - 6 * ((dil) * (512 / (6 * (dil))))) + 3) / 4))
#define LAYER(i, nin, dil) \
    msd_layer<nin, dil><<<GBLK(dil), 256, 0, stream>>>((const float*)d_in[2 + i], bias, out, i)

    LAYER(0, 1, 1);
    LAYER(1, 3, 2);
    LAYER(2, 5, 3);
    LAYER(3, 7, 4);
    LAYER(4, 9, 5);
    LAYER(5, 11, 6);
    LAYER(6, 13, 7);
    LAYER(7, 15, 8);
    LAYER(8, 17, 9);
    LAYER(9, 19, 10);
    LAYER(10, 21, 11);
    LAYER(11, 23, 12);
#undef LAYER
#undef GBLK
}